// Round 5
// baseline (1004.793 us; speedup 1.0000x reference)
//
#include <hip/hip_runtime.h>
#include <hip/hip_bf16.h>

// AtomicScaleModule — CGCNN GNN forward, MFMA split-bf16 (~f32 accuracy).
// One 16-atom group per wave (lean registers, 2x grid for latency hiding).
//   a = X@AE + ae_b
//   per layer: s = a@MW1[0:64]+b1 ; t = a@MW1[64:128]   (fused into producer)
//              H = sum_c relu(s + t[idx])               (gather @ head of dense)
//              agg = H@MW2 + 12*b2
//              u1 = relu(a@UW1[0:64] + agg@UW1[64:128] + ub1)
//              a' = relu(a + u1@UW2 + ub2)  (+ fused s,t of next layer)
//   af = relu(a@FX1+fb1)@FX2+fb2 ; props = af@PW^T+pb   (fused into last dense)
// S/T double-buffered across layers. nbr_fea / ne_w / ne_b dead.

constexpr int NA = 300000;

typedef short  s16x8 __attribute__((ext_vector_type(8)));
typedef float  f32x4 __attribute__((ext_vector_type(4)));

#define DEVFN static __device__ __forceinline__

DEVFN unsigned short f2bf(float x) {
  unsigned u = __float_as_uint(x);
  u += 0x7fffu + ((u >> 16) & 1u);          // RTNE
  return (unsigned short)(u >> 16);
}
DEVFN float bf2f(unsigned short h) { return __uint_as_float(((unsigned)h) << 16); }

// split x -> hi + lo bf16 pair (v_cvt_pk_bf16_f32-friendly)
DEVFN void mk_frag(const float* v, s16x8& hi, s16x8& lo) {
#pragma unroll
  for (int i = 0; i < 8; i += 2) {
    __hip_bfloat162 h2 = __float22bfloat162_rn(make_float2(v[i], v[i + 1]));
    float2 hf = __bfloat1622float2(h2);
    __hip_bfloat162 l2 = __float22bfloat162_rn(make_float2(v[i] - hf.x, v[i + 1] - hf.y));
    hi[i]     = (short)__bfloat16_as_ushort(h2.x);
    hi[i + 1] = (short)__bfloat16_as_ushort(h2.y);
    lo[i]     = (short)__bfloat16_as_ushort(l2.x);
    lo[i + 1] = (short)__bfloat16_as_ushort(l2.y);
  }
}

DEVFN f32x4 mf3(s16x8 ah, s16x8 al, s16x8 bh, s16x8 bl, f32x4 c) {
  c = __builtin_amdgcn_mfma_f32_16x16x32_bf16(al, bh, c, 0, 0, 0);
  c = __builtin_amdgcn_mfma_f32_16x16x32_bf16(ah, bl, c, 0, 0, 0);
  c = __builtin_amdgcn_mfma_f32_16x16x32_bf16(ah, bh, c, 0, 0, 0);
  return c;
}

DEVFN void ldB(const unsigned short* __restrict__ WH, const unsigned short* __restrict__ WL,
               int seg, int kt, int ct, int CT, int l, s16x8& bh, s16x8& bl) {
  size_t o = (size_t)seg + ((size_t)((kt * CT + ct) * 64 + l)) * 8;
  bh = *(const s16x8*)(WH + o);
  bl = *(const s16x8*)(WL + o);
}

DEVFN void ldA_g(const float* __restrict__ p8, s16x8& hi, s16x8& lo) {
  f32x4 a = *(const f32x4*)p8;
  f32x4 b = *(const f32x4*)(p8 + 4);
  float v[8] = {a[0], a[1], a[2], a[3], b[0], b[1], b[2], b[3]};
  mk_frag(v, hi, lo);
}

// Wave-private transposed slab: sl[feature][atom(0..15)], pad 17.
// Same-wave LDS is in-order; compiler preserves may-alias ordering -> no fences.
template <int NCT>
DEVFN void c_to_slab(float (*sl)[17], int m, int g, const f32x4 (&c)[NCT]) {
#pragma unroll
  for (int ct = 0; ct < NCT; ++ct)
#pragma unroll
    for (int r = 0; r < 4; ++r)
      sl[16 * ct + m][4 * g + r] = c[ct][r];
}

DEVFN void slab_frag(const float (*sl)[17], int m, int g, int kt, s16x8& hi, s16x8& lo) {
  float v[8];
#pragma unroll
  for (int i = 0; i < 8; ++i) v[i] = sl[32 * kt + 8 * g + i][m];
  mk_frag(v, hi, lo);
}

DEVFN void slab_store64(const float (*sl)[17], int m, int g, float* __restrict__ row, bool ok) {
  if (!ok) return;
#pragma unroll
  for (int p = 0; p < 4; ++p) {
    float4 q = make_float4(sl[16 * g + 4 * p + 0][m], sl[16 * g + 4 * p + 1][m],
                           sl[16 * g + 4 * p + 2][m], sl[16 * g + 4 * p + 3][m]);
    *(float4*)(row + 16 * g + 4 * p) = q;
  }
}

DEVFN void slab_storeT(const float (*sl)[17], int m, int g, unsigned short* __restrict__ row, bool ok) {
  if (!ok) return;
#pragma unroll
  for (int h = 0; h < 2; ++h) {
    uint4 q;
    unsigned* qp = (unsigned*)&q;
#pragma unroll
    for (int p = 0; p < 4; ++p) {
      float a = sl[16 * g + 8 * h + 2 * p + 0][m];
      float b = sl[16 * g + 8 * h + 2 * p + 1][m];
      qp[p] = (unsigned)f2bf(a) | ((unsigned)f2bf(b) << 16);
    }
    *(uint4*)(row + 16 * g + 8 * h) = q;
  }
}

DEVFN f32x4 bias4(float bv) { f32x4 c; c[0] = bv; c[1] = bv; c[2] = bv; c[3] = bv; return c; }

// ---- weight pre-conversion to B-frag layout (hi/lo bf16) ------------------
// Segments (entry offsets): AE 0 (96x64); per layer base=6144+l*24576:
//   MW1 +0 (128x64), MW2 +8192 (64x64), UW1 +12288 (128x64), UW2 +20480 (64x64)
// FX1 79872 (64x128), FX2 88064 (128x64). Total 96256 entries.
__global__ __launch_bounds__(256) void k_prep(
    const float* __restrict__ ae, const float* __restrict__ mw1,
    const float* __restrict__ mw2, const float* __restrict__ uw1,
    const float* __restrict__ uw2, const float* __restrict__ fx1,
    const float* __restrict__ fx2,
    unsigned short* __restrict__ WH, unsigned short* __restrict__ WL) {
  int e = blockIdx.x * 256 + threadIdx.x;
  const float* src;
  int K, N, loc;
  if (e < 6144) { src = ae; K = 92; N = 64; loc = e; }
  else if (e < 79872) {
    int r = e - 6144;
    int lyr = r / 24576, q = r % 24576;
    size_t l64 = (size_t)lyr * 64;
    if (q < 8192)       { src = mw1 + l64 * 128; K = 128; N = 64; loc = q; }
    else if (q < 12288) { src = mw2 + l64 * 64;  K = 64;  N = 64; loc = q - 8192; }
    else if (q < 20480) { src = uw1 + l64 * 128; K = 128; N = 64; loc = q - 12288; }
    else                { src = uw2 + l64 * 64;  K = 64;  N = 64; loc = q - 20480; }
  }
  else if (e < 88064) { src = fx1; K = 64;  N = 128; loc = e - 79872; }
  else if (e < 96256) { src = fx2; K = 128; N = 64;  loc = e - 88064; }
  else return;
  int k = (N == 64) ? (loc >> 6) : (loc >> 7);
  int j = loc & (N - 1);
  float v = (k < K) ? src[(size_t)k * N + j] : 0.f;
  unsigned short h = f2bf(v);
  int CT = N >> 4;
  int lane = ((k >> 3) & 3) * 16 + (j & 15);
  int fidx = (e - loc) + (((k >> 5) * CT + (j >> 4)) * 64 + lane) * 8 + (k & 7);
  WH[fidx] = h;
  WL[fidx] = f2bf(v - bf2f(h));
}

// ---- embed + s,t of layer 0 (16 atoms per wave) ---------------------------
__global__ __launch_bounds__(256) void k_embed_st(
    const float* __restrict__ X,
    const unsigned short* __restrict__ WH, const unsigned short* __restrict__ WL,
    const float* __restrict__ aeb, const float* __restrict__ b1,
    float* __restrict__ A0, float* __restrict__ S, unsigned short* __restrict__ T) {
  __shared__ float slab[4][64][17];
  int w = threadIdx.x >> 6, l = threadIdx.x & 63, m = l & 15, g = l >> 4;
  float (*sl)[17] = slab[w];
  int nbase = blockIdx.x * 64 + w * 16;
  int nat = nbase + m;
  bool ok = nat < NA;
  if (!ok) nat = NA - 1;

  // X fragments (K=92 padded to 96)
  s16x8 xh[3], xl[3];
  {
    const float* xr = X + (size_t)nat * 92;
#pragma unroll
    for (int kt = 0; kt < 3; ++kt) {
      float v[8];
      if (kt < 2) {
        f32x4 a = *(const f32x4*)(xr + kt * 32 + g * 8);
        f32x4 b = *(const f32x4*)(xr + kt * 32 + g * 8 + 4);
        v[0]=a[0]; v[1]=a[1]; v[2]=a[2]; v[3]=a[3]; v[4]=b[0]; v[5]=b[1]; v[6]=b[2]; v[7]=b[3];
      } else if (g < 3) {
        f32x4 a = *(const f32x4*)(xr + 64 + g * 8);
        f32x4 b = *(const f32x4*)(xr + 64 + g * 8 + 4);
        v[0]=a[0]; v[1]=a[1]; v[2]=a[2]; v[3]=a[3]; v[4]=b[0]; v[5]=b[1]; v[6]=b[2]; v[7]=b[3];
      } else {
        f32x4 a = *(const f32x4*)(xr + 88);   // 88..91 valid, 92..95 pad
        v[0]=a[0]; v[1]=a[1]; v[2]=a[2]; v[3]=a[3]; v[4]=0.f; v[5]=0.f; v[6]=0.f; v[7]=0.f;
      }
      mk_frag(v, xh[kt], xl[kt]);
    }
  }

  // a0 = X@AE + ae_b (bias in acc init)
  f32x4 ca[4];
#pragma unroll
  for (int ct = 0; ct < 4; ++ct) ca[ct] = bias4(aeb[16 * ct + m]);
#pragma unroll
  for (int ct = 0; ct < 4; ++ct)
#pragma unroll
    for (int kt = 0; kt < 3; ++kt) {
      s16x8 bh, bl; ldB(WH, WL, 0, kt, ct, 4, l, bh, bl);
      ca[ct] = mf3(xh[kt], xl[kt], bh, bl, ca[ct]);
    }

  s16x8 ah[2], al[2];
  c_to_slab<4>(sl, m, g, ca);
  slab_store64(sl, m, g, A0 + (size_t)nat * 64, ok);
  slab_frag(sl, m, g, 0, ah[0], al[0]);
  slab_frag(sl, m, g, 1, ah[1], al[1]);

  // s = a0@MW1[0:64] + b1
  f32x4 cs[4];
#pragma unroll
  for (int ct = 0; ct < 4; ++ct) cs[ct] = bias4(b1[16 * ct + m]);
#pragma unroll
  for (int ct = 0; ct < 4; ++ct)
#pragma unroll
    for (int kt = 0; kt < 2; ++kt) {
      s16x8 bh, bl; ldB(WH, WL, 6144, kt, ct, 4, l, bh, bl);
      cs[ct] = mf3(ah[kt], al[kt], bh, bl, cs[ct]);
    }
  c_to_slab<4>(sl, m, g, cs);
  slab_store64(sl, m, g, S + (size_t)nat * 64, ok);

  // t = a0@MW1[64:128]
  f32x4 cT[4];
#pragma unroll
  for (int ct = 0; ct < 4; ++ct) cT[ct] = bias4(0.f);
#pragma unroll
  for (int ct = 0; ct < 4; ++ct)
#pragma unroll
    for (int kt = 0; kt < 2; ++kt) {
      s16x8 bh, bl; ldB(WH, WL, 6144, kt + 2, ct, 4, l, bh, bl);
      cT[ct] = mf3(ah[kt], al[kt], bh, bl, cT[ct]);
    }
  c_to_slab<4>(sl, m, g, cT);
  slab_storeT(sl, m, g, T + (size_t)nat * 64, ok);
}

// ---- fused: gather + dense chain (+ next-layer s,t | + fx tail) -----------
template <int HAS_NEXT, int HAS_FX>
__global__ __launch_bounds__(256) void k_dense(
    const float* __restrict__ A, const float* __restrict__ S,
    const unsigned short* __restrict__ T, const int* __restrict__ IDX,
    const unsigned short* __restrict__ WH, const unsigned short* __restrict__ WL,
    int segW2, int segU1, int segU2, int segWn,
    const float* __restrict__ b2, const float* __restrict__ ub1,
    const float* __restrict__ ub2, const float* __restrict__ bn,
    const float* __restrict__ fb1, const float* __restrict__ fb2,
    const float* __restrict__ PW, const float* __restrict__ PB,
    float* __restrict__ Anew, float* __restrict__ Sout,
    unsigned short* __restrict__ Tout,
    float* __restrict__ AF, float* __restrict__ PR) {
  __shared__ float slab[4][HAS_FX ? 128 : 64][17];
  int w = threadIdx.x >> 6, l = threadIdx.x & 63, m = l & 15, g = l >> 4;
  float (*sl)[17] = slab[w];
  int nbase = blockIdx.x * 64 + w * 16;
  int nat = nbase + m;
  bool ok = nat < NA;
  if (!ok) nat = NA - 1;

  // gather: H = sum_c relu(s + t[idx]); fragments built directly.
  s16x8 hh[2], hl[2];
  {
    const int* ip = IDX + (size_t)nat * 12;
    int4 i0 = *(const int4*)ip;
    int4 i1 = *(const int4*)(ip + 4);
    int4 i2 = *(const int4*)(ip + 8);
    int idxs[12] = {i0.x, i0.y, i0.z, i0.w, i1.x, i1.y, i1.z, i1.w,
                    i2.x, i2.y, i2.z, i2.w};
#pragma unroll
    for (int kt = 0; kt < 2; ++kt) {
      int f0 = 32 * kt + 8 * g;
      const float* sp = S + (size_t)nat * 64 + f0;
      f32x4 s0 = *(const f32x4*)sp;
      f32x4 s1 = *(const f32x4*)(sp + 4);
      float h[8] = {0, 0, 0, 0, 0, 0, 0, 0};
#pragma unroll
      for (int c = 0; c < 12; ++c) {
        uint4 tv = *(const uint4*)(T + (size_t)idxs[c] * 64 + f0);
        h[0] += fmaxf(s0[0] + bf2f((unsigned short)(tv.x & 0xffff)), 0.f);
        h[1] += fmaxf(s0[1] + bf2f((unsigned short)(tv.x >> 16)), 0.f);
        h[2] += fmaxf(s0[2] + bf2f((unsigned short)(tv.y & 0xffff)), 0.f);
        h[3] += fmaxf(s0[3] + bf2f((unsigned short)(tv.y >> 16)), 0.f);
        h[4] += fmaxf(s1[0] + bf2f((unsigned short)(tv.z & 0xffff)), 0.f);
        h[5] += fmaxf(s1[1] + bf2f((unsigned short)(tv.z >> 16)), 0.f);
        h[6] += fmaxf(s1[2] + bf2f((unsigned short)(tv.w & 0xffff)), 0.f);
        h[7] += fmaxf(s1[3] + bf2f((unsigned short)(tv.w >> 16)), 0.f);
      }
      mk_frag(h, hh[kt], hl[kt]);
    }
  }

  // agg = H@W2 + 12*b2
  f32x4 cg[4];
#pragma unroll
  for (int ct = 0; ct < 4; ++ct) cg[ct] = bias4(12.f * b2[16 * ct + m]);
#pragma unroll
  for (int ct = 0; ct < 4; ++ct)
#pragma unroll
    for (int kt = 0; kt < 2; ++kt) {
      s16x8 bh, bl; ldB(WH, WL, segW2, kt, ct, 4, l, bh, bl);
      cg[ct] = mf3(hh[kt], hl[kt], bh, bl, cg[ct]);
    }

  s16x8 qh[2], ql[2];
  c_to_slab<4>(sl, m, g, cg);
  slab_frag(sl, m, g, 0, qh[0], ql[0]);
  slab_frag(sl, m, g, 1, qh[1], ql[1]);

  s16x8 arh[2], arl[2];
#pragma unroll
  for (int kt = 0; kt < 2; ++kt)
    ldA_g(A + (size_t)nat * 64 + kt * 32 + g * 8, arh[kt], arl[kt]);

  // u1 = relu(a@U1[0:64] + agg@U1[64:128] + ub1)
  f32x4 cu[4];
#pragma unroll
  for (int ct = 0; ct < 4; ++ct) cu[ct] = bias4(ub1[16 * ct + m]);
#pragma unroll
  for (int ct = 0; ct < 4; ++ct) {
#pragma unroll
    for (int kt = 0; kt < 2; ++kt) {
      s16x8 bh, bl; ldB(WH, WL, segU1, kt, ct, 4, l, bh, bl);
      cu[ct] = mf3(arh[kt], arl[kt], bh, bl, cu[ct]);
    }
#pragma unroll
    for (int kt = 0; kt < 2; ++kt) {
      s16x8 bh, bl; ldB(WH, WL, segU1, kt + 2, ct, 4, l, bh, bl);
      cu[ct] = mf3(qh[kt], ql[kt], bh, bl, cu[ct]);
    }
  }
#pragma unroll
  for (int ct = 0; ct < 4; ++ct)
#pragma unroll
    for (int r = 0; r < 4; ++r) cu[ct][r] = fmaxf(cu[ct][r], 0.f);

  s16x8 uh[2], ul[2];
  c_to_slab<4>(sl, m, g, cu);
  slab_frag(sl, m, g, 0, uh[0], ul[0]);
  slab_frag(sl, m, g, 1, uh[1], ul[1]);

  // upd = u1@U2 + ub2 ; a' = relu(a + upd)
  f32x4 cd[4];
#pragma unroll
  for (int ct = 0; ct < 4; ++ct) cd[ct] = bias4(ub2[16 * ct + m]);
#pragma unroll
  for (int ct = 0; ct < 4; ++ct)
#pragma unroll
    for (int kt = 0; kt < 2; ++kt) {
      s16x8 bh, bl; ldB(WH, WL, segU2, kt, ct, 4, l, bh, bl);
      cd[ct] = mf3(uh[kt], ul[kt], bh, bl, cd[ct]);
    }
#pragma unroll
  for (int ct = 0; ct < 4; ++ct)
#pragma unroll
    for (int r = 0; r < 4; ++r) {
      int nr = nbase + 4 * g + r;
      if (nr > NA - 1) nr = NA - 1;
      float av = A[(size_t)nr * 64 + 16 * ct + m];
      cd[ct][r] = fmaxf(av + cd[ct][r], 0.f);
    }

  s16x8 anh[2], anl[2];
  c_to_slab<4>(sl, m, g, cd);
  slab_store64(sl, m, g, Anew + (size_t)nat * 64, ok);
  if constexpr (HAS_NEXT || HAS_FX) {
    slab_frag(sl, m, g, 0, anh[0], anl[0]);
    slab_frag(sl, m, g, 1, anh[1], anl[1]);
  }

  if constexpr (HAS_NEXT) {
    // s_next
    f32x4 cs[4];
#pragma unroll
    for (int ct = 0; ct < 4; ++ct) cs[ct] = bias4(bn[16 * ct + m]);
#pragma unroll
    for (int ct = 0; ct < 4; ++ct)
#pragma unroll
      for (int kt = 0; kt < 2; ++kt) {
        s16x8 bh, bl; ldB(WH, WL, segWn, kt, ct, 4, l, bh, bl);
        cs[ct] = mf3(anh[kt], anl[kt], bh, bl, cs[ct]);
      }
    c_to_slab<4>(sl, m, g, cs);
    slab_store64(sl, m, g, Sout + (size_t)nat * 64, ok);

    // t_next
    f32x4 cT[4];
#pragma unroll
    for (int ct = 0; ct < 4; ++ct) cT[ct] = bias4(0.f);
#pragma unroll
    for (int ct = 0; ct < 4; ++ct)
#pragma unroll
      for (int kt = 0; kt < 2; ++kt) {
        s16x8 bh, bl; ldB(WH, WL, segWn, kt + 2, ct, 4, l, bh, bl);
        cT[ct] = mf3(anh[kt], anl[kt], bh, bl, cT[ct]);
      }
    c_to_slab<4>(sl, m, g, cT);
    slab_storeT(sl, m, g, Tout + (size_t)nat * 64, ok);
  }

  if constexpr (HAS_FX) {
    // h = relu(raw@FX1 + fb1)  (128 wide)
    f32x4 ch[8];
#pragma unroll
    for (int ct = 0; ct < 8; ++ct) ch[ct] = bias4(fb1[16 * ct + m]);
#pragma unroll
    for (int ct = 0; ct < 8; ++ct)
#pragma unroll
      for (int kt = 0; kt < 2; ++kt) {
        s16x8 bh, bl; ldB(WH, WL, 79872, kt, ct, 8, l, bh, bl);
        ch[ct] = mf3(anh[kt], anl[kt], bh, bl, ch[ct]);
      }
#pragma unroll
    for (int ct = 0; ct < 8; ++ct)
#pragma unroll
      for (int r = 0; r < 4; ++r) ch[ct][r] = fmaxf(ch[ct][r], 0.f);

    s16x8 hfh[4], hfl[4];
    c_to_slab<8>(sl, m, g, ch);
#pragma unroll
    for (int kt = 0; kt < 4; ++kt) slab_frag(sl, m, g, kt, hfh[kt], hfl[kt]);

    // af = h@FX2 + fb2
    f32x4 cf[4];
#pragma unroll
    for (int ct = 0; ct < 4; ++ct) cf[ct] = bias4(fb2[16 * ct + m]);
#pragma unroll
    for (int ct = 0; ct < 4; ++ct)
#pragma unroll
      for (int kt = 0; kt < 4; ++kt) {
        s16x8 bh, bl; ldB(WH, WL, 88064, kt, ct, 4, l, bh, bl);
        cf[ct] = mf3(hfh[kt], hfl[kt], bh, bl, cf[ct]);
      }

    c_to_slab<4>(sl, m, g, cf);
    slab_store64(sl, m, g, AF + (size_t)nat * 64, ok);
    float acc = PB[g];
#pragma unroll 8
    for (int f = 0; f < 64; ++f) acc += sl[f][m] * PW[g * 64 + f];
    if (ok) PR[(size_t)nat * 4 + g] = acc;
  }
}

extern "C" void kernel_launch(void* const* d_in, const int* in_sizes, int n_in,
                              void* d_out, int out_size, void* d_ws, size_t ws_size,
                              hipStream_t stream) {
  const float* atom_fea = (const float*)d_in[0];
  const int*   nbr_idx  = (const int*)d_in[2];
  const float* ae_w   = (const float*)d_in[3];
  const float* ae_b   = (const float*)d_in[4];
  const float* msg_w1 = (const float*)d_in[7];
  const float* msg_b1 = (const float*)d_in[8];
  const float* msg_w2 = (const float*)d_in[9];
  const float* msg_b2 = (const float*)d_in[10];
  const float* upd_w1 = (const float*)d_in[11];
  const float* upd_b1 = (const float*)d_in[12];
  const float* upd_w2 = (const float*)d_in[13];
  const float* upd_b2 = (const float*)d_in[14];
  const float* fx_w1  = (const float*)d_in[15];
  const float* fx_b1  = (const float*)d_in[16];
  const float* fx_w2  = (const float*)d_in[17];
  const float* fx_b2  = (const float*)d_in[18];
  const float* prop_w = (const float*)d_in[19];
  const float* prop_b = (const float*)d_in[20];

  float* props   = (float*)d_out;
  float* af_reg  = props + (size_t)NA * 4;
  float* raw_reg = af_reg + (size_t)NA * 64;
  float* S0 = (float*)d_ws;
  float* S1 = S0 + (size_t)NA * 64;
  unsigned short* T0 = (unsigned short*)(S1 + (size_t)NA * 64);
  unsigned short* T1 = T0 + (size_t)NA * 64;
  unsigned short* WHp = T1 + (size_t)NA * 64;
  unsigned short* WLp = WHp + 96256;

  k_prep<<<376, 256, 0, stream>>>(ae_w, msg_w1, msg_w2, upd_w1, upd_w2,
                                  fx_w1, fx_w2, WHp, WLp);

  int ngrid = (NA + 63) / 64;   // 4688
  k_embed_st<<<ngrid, 256, 0, stream>>>(atom_fea, WHp, WLp, ae_b, msg_b1,
                                        af_reg, S0, T0);

  const int base0 = 6144, base1 = 6144 + 24576, base2 = 6144 + 2 * 24576;

  // layer 0: A0(af_reg) -> A1(raw_reg); S0/T0 -> S1/T1
  k_dense<1, 0><<<ngrid, 256, 0, stream>>>(
      af_reg, S0, T0, nbr_idx, WHp, WLp,
      base0 + 8192, base0 + 12288, base0 + 20480, base1,
      msg_b2, upd_b1, upd_b2, msg_b1 + 64,
      fx_b1, fx_b2, prop_w, prop_b,
      raw_reg, S1, T1, nullptr, nullptr);

  // layer 1: A1(raw_reg) -> A2(af_reg); S1/T1 -> S0/T0
  k_dense<1, 0><<<ngrid, 256, 0, stream>>>(
      raw_reg, S1, T1, nbr_idx, WHp, WLp,
      base1 + 8192, base1 + 12288, base1 + 20480, base2,
      msg_b2 + 64, upd_b1 + 64, upd_b2 + 64, msg_b1 + 128,
      fx_b1, fx_b2, prop_w, prop_b,
      af_reg, S0, T0, nullptr, nullptr);

  // layer 2 + fx: A2(af_reg) -> raw(raw_reg); af->af_reg, props->d_out
  k_dense<0, 1><<<ngrid, 256, 0, stream>>>(
      af_reg, S0, T0, nbr_idx, WHp, WLp,
      base2 + 8192, base2 + 12288, base2 + 20480, 0,
      msg_b2 + 128, upd_b1 + 128, upd_b2 + 128, msg_b1,
      fx_b1, fx_b2, prop_w, prop_b,
      raw_reg, S1, T1, af_reg, props);
}

// Round 6
// 692.993 us; speedup vs baseline: 1.4499x; 1.4499x over previous
//
#include <hip/hip_runtime.h>
#include <hip/hip_bf16.h>

// AtomicScaleModule — CGCNN GNN forward, MFMA split-bf16 (~f32 accuracy).
// 4 groups (64 atoms) per wave: each weight-fragment load feeds 4 MFMAs,
// per-wave serial chain amortized over 64 atoms (R5 post-mortem: chains are
// latency-bound; amortization/ILP wins, not wave count).
//   a = X@AE + ae_b
//   per layer: s = a@MW1[0:64]+b1 ; t = a@MW1[64:128]   (fused into producer)
//              H = sum_c relu(s + t[idx])               (gather @ head of dense)
//              agg = H@MW2 + 12*b2
//              u1 = relu(a@UW1[0:64] + agg@UW1[64:128] + ub1)
//              a' = relu(a + u1@UW2 + ub2)  (+ fused s,t of next layer)
//   af = relu(a@FX1+fb1)@FX2+fb2 ; props = af@PW^T+pb   (fused into last dense)
// S/T double-buffered across layers. nbr_fea / ne_w / ne_b dead.

constexpr int NA = 300000;

typedef short  s16x8 __attribute__((ext_vector_type(8)));
typedef float  f32x4 __attribute__((ext_vector_type(4)));

#define DEVFN static __device__ __forceinline__

DEVFN unsigned short f2bf(float x) {
  unsigned u = __float_as_uint(x);
  u += 0x7fffu + ((u >> 16) & 1u);          // RTNE
  return (unsigned short)(u >> 16);
}
DEVFN float bf2f(unsigned short h) { return __uint_as_float(((unsigned)h) << 16); }

// split x -> hi + lo bf16 pair (v_cvt_pk_bf16_f32-friendly)
DEVFN void mk_frag(const float* v, s16x8& hi, s16x8& lo) {
#pragma unroll
  for (int i = 0; i < 8; i += 2) {
    __hip_bfloat162 h2 = __float22bfloat162_rn(make_float2(v[i], v[i + 1]));
    float2 hf = __bfloat1622float2(h2);
    __hip_bfloat162 l2 = __float22bfloat162_rn(make_float2(v[i] - hf.x, v[i + 1] - hf.y));
    hi[i]     = (short)__bfloat16_as_ushort(h2.x);
    hi[i + 1] = (short)__bfloat16_as_ushort(h2.y);
    lo[i]     = (short)__bfloat16_as_ushort(l2.x);
    lo[i + 1] = (short)__bfloat16_as_ushort(l2.y);
  }
}

DEVFN f32x4 mf3(s16x8 ah, s16x8 al, s16x8 bh, s16x8 bl, f32x4 c) {
  c = __builtin_amdgcn_mfma_f32_16x16x32_bf16(al, bh, c, 0, 0, 0);
  c = __builtin_amdgcn_mfma_f32_16x16x32_bf16(ah, bl, c, 0, 0, 0);
  c = __builtin_amdgcn_mfma_f32_16x16x32_bf16(ah, bh, c, 0, 0, 0);
  return c;
}

DEVFN void ldB(const unsigned short* __restrict__ WH, const unsigned short* __restrict__ WL,
               int seg, int kt, int ct, int CT, int l, s16x8& bh, s16x8& bl) {
  size_t o = (size_t)seg + ((size_t)((kt * CT + ct) * 64 + l)) * 8;
  bh = *(const s16x8*)(WH + o);
  bl = *(const s16x8*)(WL + o);
}

DEVFN void lds_fence() { asm volatile("s_waitcnt lgkmcnt(0)" ::: "memory"); }
DEVFN f32x4 bias4(float bv) { f32x4 c; c[0] = bv; c[1] = bv; c[2] = bv; c[3] = bv; return c; }

// one 64x64 GEMM stage for all 4 groups: 8 B-pairs, 96 MFMA.
DEVFN void stage_mm(const unsigned short* __restrict__ WH,
                    const unsigned short* __restrict__ WL,
                    int seg, int kt0,
                    const s16x8 (&fh)[4][2], const s16x8 (&fl)[4][2],
                    int l, f32x4 (&cc)[4][4]) {
#pragma unroll
  for (int ct = 0; ct < 4; ++ct)
#pragma unroll
    for (int kt = 0; kt < 2; ++kt) {
      s16x8 bh, bl; ldB(WH, WL, seg, kt0 + kt, ct, 4, l, bh, bl);
#pragma unroll
      for (int gr = 0; gr < 4; ++gr)
        cc[gr][ct] = mf3(fh[gr][kt], fl[gr][kt], bh, bl, cc[gr][ct]);
    }
}

// Wave-private transposed slab: sl[feature(64)][4 groups * 17], col = gr*17+atom.
// C value (row=4g+r, col=16ct+m) of group gr -> sl[16ct+m][gr*17 + 4g+r].
DEVFN void slab_put4(float (*sl)[69], int m, int g, const f32x4 (&cc)[4][4]) {
  lds_fence();
#pragma unroll
  for (int gr = 0; gr < 4; ++gr)
#pragma unroll
    for (int ct = 0; ct < 4; ++ct)
#pragma unroll
      for (int r = 0; r < 4; ++r)
        sl[16 * ct + m][gr * 17 + 4 * g + r] = cc[gr][ct][r];
  lds_fence();
}

// A-fragments for all 4 groups: atom=m of group gr, k = 32kt + 8g + i.
DEVFN void slab_get4(const float (*sl)[69], int m, int g,
                     s16x8 (&fh)[4][2], s16x8 (&fl)[4][2]) {
#pragma unroll
  for (int gr = 0; gr < 4; ++gr)
#pragma unroll
    for (int kt = 0; kt < 2; ++kt) {
      float v[8];
#pragma unroll
      for (int i = 0; i < 8; ++i) v[i] = sl[32 * kt + 8 * g + i][gr * 17 + m];
      mk_frag(v, fh[gr][kt], fl[gr][kt]);
    }
}

DEVFN void slab_out64(const float (*sl)[69], int col, int g,
                      float* __restrict__ row, bool ok) {
  if (!ok) return;
#pragma unroll
  for (int p = 0; p < 4; ++p) {
    float4 q = make_float4(sl[16 * g + 4 * p + 0][col], sl[16 * g + 4 * p + 1][col],
                           sl[16 * g + 4 * p + 2][col], sl[16 * g + 4 * p + 3][col]);
    *(float4*)(row + 16 * g + 4 * p) = q;
  }
}

DEVFN void slab_outT(const float (*sl)[69], int col, int g,
                     unsigned short* __restrict__ row, bool ok) {
  if (!ok) return;
#pragma unroll
  for (int h = 0; h < 2; ++h) {
    uint4 q;
    unsigned* qp = (unsigned*)&q;
#pragma unroll
    for (int p = 0; p < 4; ++p) {
      float a = sl[16 * g + 8 * h + 2 * p + 0][col];
      float b = sl[16 * g + 8 * h + 2 * p + 1][col];
      qp[p] = (unsigned)f2bf(a) | ((unsigned)f2bf(b) << 16);
    }
    *(uint4*)(row + 16 * g + 8 * h) = q;
  }
}

// ---- weight pre-conversion to B-frag layout (hi/lo bf16) ------------------
// Segments (entry offsets): AE 0 (96x64); per layer base=6144+l*24576:
//   MW1 +0 (128x64), MW2 +8192 (64x64), UW1 +12288 (128x64), UW2 +20480 (64x64)
// FX1 79872 (64x128), FX2 88064 (128x64). Total 96256 entries.
__global__ __launch_bounds__(256) void k_prep(
    const float* __restrict__ ae, const float* __restrict__ mw1,
    const float* __restrict__ mw2, const float* __restrict__ uw1,
    const float* __restrict__ uw2, const float* __restrict__ fx1,
    const float* __restrict__ fx2,
    unsigned short* __restrict__ WH, unsigned short* __restrict__ WL) {
  int e = blockIdx.x * 256 + threadIdx.x;
  const float* src;
  int K, N, loc;
  if (e < 6144) { src = ae; K = 92; N = 64; loc = e; }
  else if (e < 79872) {
    int r = e - 6144;
    int lyr = r / 24576, q = r % 24576;
    size_t l64 = (size_t)lyr * 64;
    if (q < 8192)       { src = mw1 + l64 * 128; K = 128; N = 64; loc = q; }
    else if (q < 12288) { src = mw2 + l64 * 64;  K = 64;  N = 64; loc = q - 8192; }
    else if (q < 20480) { src = uw1 + l64 * 128; K = 128; N = 64; loc = q - 12288; }
    else                { src = uw2 + l64 * 64;  K = 64;  N = 64; loc = q - 20480; }
  }
  else if (e < 88064) { src = fx1; K = 64;  N = 128; loc = e - 79872; }
  else if (e < 96256) { src = fx2; K = 128; N = 64;  loc = e - 88064; }
  else return;
  int k = (N == 64) ? (loc >> 6) : (loc >> 7);
  int j = loc & (N - 1);
  float v = (k < K) ? src[(size_t)k * N + j] : 0.f;
  unsigned short h = f2bf(v);
  int CT = N >> 4;
  int lane = ((k >> 3) & 3) * 16 + (j & 15);
  int fidx = (e - loc) + (((k >> 5) * CT + (j >> 4)) * 64 + lane) * 8 + (k & 7);
  WH[fidx] = h;
  WL[fidx] = f2bf(v - bf2f(h));
}

// ---- embed + s,t of layer 0 (64 atoms per wave) ---------------------------
__global__ __launch_bounds__(256, 2) void k_embed_st(
    const float* __restrict__ X,
    const unsigned short* __restrict__ WH, const unsigned short* __restrict__ WL,
    const float* __restrict__ aeb, const float* __restrict__ b1,
    float* __restrict__ A0, float* __restrict__ S, unsigned short* __restrict__ T) {
  __shared__ float slab[4][64][69];
  int w = threadIdx.x >> 6, l = threadIdx.x & 63, m = l & 15, g = l >> 4;
  float (*sl)[69] = slab[w];
  int nbase = blockIdx.x * 256 + w * 64;
  int nat[4]; bool ok[4];
#pragma unroll
  for (int gr = 0; gr < 4; ++gr) {
    nat[gr] = nbase + gr * 16 + m;
    ok[gr] = nat[gr] < NA;
    if (!ok[gr]) nat[gr] = NA - 1;
  }

  // a0 = X@AE + ae_b ; X fragments built per kt to bound liveness
  f32x4 ca[4][4];
#pragma unroll
  for (int gr = 0; gr < 4; ++gr)
#pragma unroll
    for (int ct = 0; ct < 4; ++ct) ca[gr][ct] = bias4(aeb[16 * ct + m]);
#pragma unroll
  for (int kt = 0; kt < 3; ++kt) {
    s16x8 xh[4], xl[4];
#pragma unroll
    for (int gr = 0; gr < 4; ++gr) {
      const float* xr = X + (size_t)nat[gr] * 92;
      float v[8];
      if (kt < 2) {
        f32x4 a = *(const f32x4*)(xr + kt * 32 + g * 8);
        f32x4 b = *(const f32x4*)(xr + kt * 32 + g * 8 + 4);
        v[0]=a[0]; v[1]=a[1]; v[2]=a[2]; v[3]=a[3]; v[4]=b[0]; v[5]=b[1]; v[6]=b[2]; v[7]=b[3];
      } else if (g < 3) {
        f32x4 a = *(const f32x4*)(xr + 64 + g * 8);
        f32x4 b = *(const f32x4*)(xr + 64 + g * 8 + 4);
        v[0]=a[0]; v[1]=a[1]; v[2]=a[2]; v[3]=a[3]; v[4]=b[0]; v[5]=b[1]; v[6]=b[2]; v[7]=b[3];
      } else {
        f32x4 a = *(const f32x4*)(xr + 88);   // 88..91 valid, 92..95 pad
        v[0]=a[0]; v[1]=a[1]; v[2]=a[2]; v[3]=a[3]; v[4]=0.f; v[5]=0.f; v[6]=0.f; v[7]=0.f;
      }
      mk_frag(v, xh[gr], xl[gr]);
    }
#pragma unroll
    for (int ct = 0; ct < 4; ++ct) {
      s16x8 bh, bl; ldB(WH, WL, 0, kt, ct, 4, l, bh, bl);
#pragma unroll
      for (int gr = 0; gr < 4; ++gr)
        ca[gr][ct] = mf3(xh[gr], xl[gr], bh, bl, ca[gr][ct]);
    }
  }

  s16x8 ah[4][2], al[4][2];
  slab_put4(sl, m, g, ca);
#pragma unroll
  for (int gr = 0; gr < 4; ++gr)
    slab_out64(sl, gr * 17 + m, g, A0 + (size_t)nat[gr] * 64, ok[gr]);
  slab_get4(sl, m, g, ah, al);

  // s = a0@MW1[0:64] + b1
  f32x4 cs[4][4];
#pragma unroll
  for (int gr = 0; gr < 4; ++gr)
#pragma unroll
    for (int ct = 0; ct < 4; ++ct) cs[gr][ct] = bias4(b1[16 * ct + m]);
  stage_mm(WH, WL, 6144, 0, ah, al, l, cs);
  slab_put4(sl, m, g, cs);
#pragma unroll
  for (int gr = 0; gr < 4; ++gr)
    slab_out64(sl, gr * 17 + m, g, S + (size_t)nat[gr] * 64, ok[gr]);

  // t = a0@MW1[64:128]
  f32x4 cT[4][4];
#pragma unroll
  for (int gr = 0; gr < 4; ++gr)
#pragma unroll
    for (int ct = 0; ct < 4; ++ct) cT[gr][ct] = bias4(0.f);
  stage_mm(WH, WL, 6144, 2, ah, al, l, cT);
  slab_put4(sl, m, g, cT);
#pragma unroll
  for (int gr = 0; gr < 4; ++gr)
    slab_outT(sl, gr * 17 + m, g, T + (size_t)nat[gr] * 64, ok[gr]);
}

// ---- fused: gather + dense chain (+ next-layer s,t | + fx tail) -----------
template <int HAS_NEXT, int HAS_FX>
__global__ __launch_bounds__(256, 2) void k_dense(
    const float* __restrict__ A, const float* __restrict__ S,
    const unsigned short* __restrict__ T, const int* __restrict__ IDX,
    const unsigned short* __restrict__ WH, const unsigned short* __restrict__ WL,
    int segW2, int segU1, int segU2, int segWn,
    const float* __restrict__ b2, const float* __restrict__ ub1,
    const float* __restrict__ ub2, const float* __restrict__ bn,
    const float* __restrict__ fb1, const float* __restrict__ fb2,
    const float* __restrict__ PW, const float* __restrict__ PB,
    float* __restrict__ Anew, float* __restrict__ Sout,
    unsigned short* __restrict__ Tout,
    float* __restrict__ AF, float* __restrict__ PR) {
  __shared__ float slab[4][64][69];
  int w = threadIdx.x >> 6, l = threadIdx.x & 63, m = l & 15, g = l >> 4;
  float (*sl)[69] = slab[w];
  int nbase = blockIdx.x * 256 + w * 64;
  int nat[4]; bool ok[4];
#pragma unroll
  for (int gr = 0; gr < 4; ++gr) {
    nat[gr] = nbase + gr * 16 + m;
    ok[gr] = nat[gr] < NA;
    if (!ok[gr]) nat[gr] = NA - 1;
  }

  // gather: H = sum_c relu(s + t[idx]); fragments built directly.
  // lanes g=0..3 at fixed m cover 64B contiguous of each T row -> coalesced.
  s16x8 hh[4][2], hl[4][2];
#pragma unroll
  for (int gr = 0; gr < 4; ++gr) {
    const int* ip = IDX + (size_t)nat[gr] * 12;
    int4 i0 = *(const int4*)ip;
    int4 i1 = *(const int4*)(ip + 4);
    int4 i2 = *(const int4*)(ip + 8);
    int idxs[12] = {i0.x, i0.y, i0.z, i0.w, i1.x, i1.y, i1.z, i1.w,
                    i2.x, i2.y, i2.z, i2.w};
#pragma unroll
    for (int kt = 0; kt < 2; ++kt) {
      int f0 = 32 * kt + 8 * g;
      const float* sp = S + (size_t)nat[gr] * 64 + f0;
      f32x4 s0 = *(const f32x4*)sp;
      f32x4 s1 = *(const f32x4*)(sp + 4);
      float h[8] = {0, 0, 0, 0, 0, 0, 0, 0};
#pragma unroll
      for (int c = 0; c < 12; ++c) {
        uint4 tv = *(const uint4*)(T + (size_t)idxs[c] * 64 + f0);
        h[0] += fmaxf(s0[0] + bf2f((unsigned short)(tv.x & 0xffff)), 0.f);
        h[1] += fmaxf(s0[1] + bf2f((unsigned short)(tv.x >> 16)), 0.f);
        h[2] += fmaxf(s0[2] + bf2f((unsigned short)(tv.y & 0xffff)), 0.f);
        h[3] += fmaxf(s0[3] + bf2f((unsigned short)(tv.y >> 16)), 0.f);
        h[4] += fmaxf(s1[0] + bf2f((unsigned short)(tv.z & 0xffff)), 0.f);
        h[5] += fmaxf(s1[1] + bf2f((unsigned short)(tv.z >> 16)), 0.f);
        h[6] += fmaxf(s1[2] + bf2f((unsigned short)(tv.w & 0xffff)), 0.f);
        h[7] += fmaxf(s1[3] + bf2f((unsigned short)(tv.w >> 16)), 0.f);
      }
      mk_frag(h, hh[gr][kt], hl[gr][kt]);
    }
  }

  // agg = H@W2 + 12*b2
  f32x4 cg[4][4];
#pragma unroll
  for (int gr = 0; gr < 4; ++gr)
#pragma unroll
    for (int ct = 0; ct < 4; ++ct) cg[gr][ct] = bias4(12.f * b2[16 * ct + m]);
  stage_mm(WH, WL, segW2, 0, hh, hl, l, cg);

  s16x8 qh[4][2], ql[4][2];
  slab_put4(sl, m, g, cg);
  slab_get4(sl, m, g, qh, ql);

  // a fragments from global
  s16x8 arh[4][2], arl[4][2];
#pragma unroll
  for (int gr = 0; gr < 4; ++gr)
#pragma unroll
    for (int kt = 0; kt < 2; ++kt) {
      const float* p8 = A + (size_t)nat[gr] * 64 + kt * 32 + g * 8;
      f32x4 a = *(const f32x4*)p8;
      f32x4 b = *(const f32x4*)(p8 + 4);
      float v[8] = {a[0], a[1], a[2], a[3], b[0], b[1], b[2], b[3]};
      mk_frag(v, arh[gr][kt], arl[gr][kt]);
    }

  // u1 = relu(a@U1[0:64] + agg@U1[64:128] + ub1)
  f32x4 cu[4][4];
#pragma unroll
  for (int gr = 0; gr < 4; ++gr)
#pragma unroll
    for (int ct = 0; ct < 4; ++ct) cu[gr][ct] = bias4(ub1[16 * ct + m]);
  stage_mm(WH, WL, segU1, 0, arh, arl, l, cu);
  stage_mm(WH, WL, segU1, 2, qh, ql, l, cu);
#pragma unroll
  for (int gr = 0; gr < 4; ++gr)
#pragma unroll
    for (int ct = 0; ct < 4; ++ct)
#pragma unroll
      for (int r = 0; r < 4; ++r) cu[gr][ct][r] = fmaxf(cu[gr][ct][r], 0.f);

  s16x8 uh[4][2], ul[4][2];
  slab_put4(sl, m, g, cu);
  slab_get4(sl, m, g, uh, ul);

  // upd = u1@U2 + ub2 ; a' = relu(a + upd)
  f32x4 cd[4][4];
#pragma unroll
  for (int gr = 0; gr < 4; ++gr)
#pragma unroll
    for (int ct = 0; ct < 4; ++ct) cd[gr][ct] = bias4(ub2[16 * ct + m]);
  stage_mm(WH, WL, segU2, 0, uh, ul, l, cd);
#pragma unroll
  for (int gr = 0; gr < 4; ++gr)
#pragma unroll
    for (int ct = 0; ct < 4; ++ct)
#pragma unroll
      for (int r = 0; r < 4; ++r) {
        int nr = nbase + gr * 16 + 4 * g + r;
        if (nr > NA - 1) nr = NA - 1;
        float av = A[(size_t)nr * 64 + 16 * ct + m];
        cd[gr][ct][r] = fmaxf(av + cd[gr][ct][r], 0.f);
      }

  s16x8 anh[4][2], anl[4][2];
  slab_put4(sl, m, g, cd);
#pragma unroll
  for (int gr = 0; gr < 4; ++gr)
    slab_out64(sl, gr * 17 + m, g, Anew + (size_t)nat[gr] * 64, ok[gr]);
  if constexpr (HAS_NEXT || HAS_FX) slab_get4(sl, m, g, anh, anl);

  if constexpr (HAS_NEXT) {
    // s_next
    f32x4 cs[4][4];
#pragma unroll
    for (int gr = 0; gr < 4; ++gr)
#pragma unroll
      for (int ct = 0; ct < 4; ++ct) cs[gr][ct] = bias4(bn[16 * ct + m]);
    stage_mm(WH, WL, segWn, 0, anh, anl, l, cs);
    slab_put4(sl, m, g, cs);
#pragma unroll
    for (int gr = 0; gr < 4; ++gr)
      slab_out64(sl, gr * 17 + m, g, Sout + (size_t)nat[gr] * 64, ok[gr]);

    // t_next
    f32x4 cT[4][4];
#pragma unroll
    for (int gr = 0; gr < 4; ++gr)
#pragma unroll
      for (int ct = 0; ct < 4; ++ct) cT[gr][ct] = bias4(0.f);
    stage_mm(WH, WL, segWn, 2, anh, anl, l, cT);
    slab_put4(sl, m, g, cT);
#pragma unroll
    for (int gr = 0; gr < 4; ++gr)
      slab_outT(sl, gr * 17 + m, g, Tout + (size_t)nat[gr] * 64, ok[gr]);
  }

  if constexpr (HAS_FX) {
    // af = relu(raw@FX1+fb1)@FX2+fb2, hidden 128 done in two 64-col rounds
    f32x4 cf[4][4];
#pragma unroll
    for (int gr = 0; gr < 4; ++gr)
#pragma unroll
      for (int ct = 0; ct < 4; ++ct) cf[gr][ct] = bias4(fb2[16 * ct + m]);

#pragma unroll
    for (int half = 0; half < 2; ++half) {
      f32x4 ch[4][4];
#pragma unroll
      for (int gr = 0; gr < 4; ++gr)
#pragma unroll
        for (int ct = 0; ct < 4; ++ct)
          ch[gr][ct] = bias4(fb1[16 * (4 * half + ct) + m]);
#pragma unroll
      for (int ct = 0; ct < 4; ++ct)
#pragma unroll
        for (int kt = 0; kt < 2; ++kt) {
          s16x8 bh, bl; ldB(WH, WL, 79872, kt, 4 * half + ct, 8, l, bh, bl);
#pragma unroll
          for (int gr = 0; gr < 4; ++gr)
            ch[gr][ct] = mf3(anh[gr][kt], anl[gr][kt], bh, bl, ch[gr][ct]);
        }
#pragma unroll
      for (int gr = 0; gr < 4; ++gr)
#pragma unroll
        for (int ct = 0; ct < 4; ++ct)
#pragma unroll
          for (int r = 0; r < 4; ++r) ch[gr][ct][r] = fmaxf(ch[gr][ct][r], 0.f);

      s16x8 hfh[4][2], hfl[4][2];
      slab_put4(sl, m, g, ch);
      slab_get4(sl, m, g, hfh, hfl);
      stage_mm(WH, WL, 88064, 2 * half, hfh, hfl, l, cf);
    }

    slab_put4(sl, m, g, cf);
#pragma unroll
    for (int gr = 0; gr < 4; ++gr) {
      slab_out64(sl, gr * 17 + m, g, AF + (size_t)nat[gr] * 64, ok[gr]);
      float acc = PB[g];
#pragma unroll 8
      for (int f = 0; f < 64; ++f) acc += sl[f][gr * 17 + m] * PW[g * 64 + f];
      if (ok[gr]) PR[(size_t)nat[gr] * 4 + g] = acc;
    }
  }
}

extern "C" void kernel_launch(void* const* d_in, const int* in_sizes, int n_in,
                              void* d_out, int out_size, void* d_ws, size_t ws_size,
                              hipStream_t stream) {
  const float* atom_fea = (const float*)d_in[0];
  const int*   nbr_idx  = (const int*)d_in[2];
  const float* ae_w   = (const float*)d_in[3];
  const float* ae_b   = (const float*)d_in[4];
  const float* msg_w1 = (const float*)d_in[7];
  const float* msg_b1 = (const float*)d_in[8];
  const float* msg_w2 = (const float*)d_in[9];
  const float* msg_b2 = (const float*)d_in[10];
  const float* upd_w1 = (const float*)d_in[11];
  const float* upd_b1 = (const float*)d_in[12];
  const float* upd_w2 = (const float*)d_in[13];
  const float* upd_b2 = (const float*)d_in[14];
  const float* fx_w1  = (const float*)d_in[15];
  const float* fx_b1  = (const float*)d_in[16];
  const float* fx_w2  = (const float*)d_in[17];
  const float* fx_b2  = (const float*)d_in[18];
  const float* prop_w = (const float*)d_in[19];
  const float* prop_b = (const float*)d_in[20];

  float* props   = (float*)d_out;
  float* af_reg  = props + (size_t)NA * 4;
  float* raw_reg = af_reg + (size_t)NA * 64;
  float* S0 = (float*)d_ws;
  float* S1 = S0 + (size_t)NA * 64;
  unsigned short* T0 = (unsigned short*)(S1 + (size_t)NA * 64);
  unsigned short* T1 = T0 + (size_t)NA * 64;
  unsigned short* WHp = T1 + (size_t)NA * 64;
  unsigned short* WLp = WHp + 96256;

  k_prep<<<376, 256, 0, stream>>>(ae_w, msg_w1, msg_w2, upd_w1, upd_w2,
                                  fx_w1, fx_w2, WHp, WLp);

  int ngrid = (NA + 255) / 256;   // 1172
  k_embed_st<<<ngrid, 256, 0, stream>>>(atom_fea, WHp, WLp, ae_b, msg_b1,
                                        af_reg, S0, T0);

  const int base0 = 6144, base1 = 6144 + 24576, base2 = 6144 + 2 * 24576;

  // layer 0: A0(af_reg) -> A1(raw_reg); S0/T0 -> S1/T1
  k_dense<1, 0><<<ngrid, 256, 0, stream>>>(
      af_reg, S0, T0, nbr_idx, WHp, WLp,
      base0 + 8192, base0 + 12288, base0 + 20480, base1,
      msg_b2, upd_b1, upd_b2, msg_b1 + 64,
      fx_b1, fx_b2, prop_w, prop_b,
      raw_reg, S1, T1, nullptr, nullptr);

  // layer 1: A1(raw_reg) -> A2(af_reg); S1/T1 -> S0/T0
  k_dense<1, 0><<<ngrid, 256, 0, stream>>>(
      raw_reg, S1, T1, nbr_idx, WHp, WLp,
      base1 + 8192, base1 + 12288, base1 + 20480, base2,
      msg_b2 + 64, upd_b1 + 64, upd_b2 + 64, msg_b1 + 128,
      fx_b1, fx_b2, prop_w, prop_b,
      af_reg, S0, T0, nullptr, nullptr);

  // layer 2 + fx: A2(af_reg) -> raw(raw_reg); af->af_reg, props->d_out
  k_dense<0, 1><<<ngrid, 256, 0, stream>>>(
      af_reg, S0, T0, nbr_idx, WHp, WLp,
      base2 + 8192, base2 + 12288, base2 + 20480, 0,
      msg_b2 + 128, upd_b1 + 128, upd_b2 + 128, msg_b1,
      fx_b1, fx_b2, prop_w, prop_b,
      raw_reg, S1, T1, af_reg, props);
}

// Round 7
// 667.258 us; speedup vs baseline: 1.5059x; 1.0386x over previous
//
#include <hip/hip_runtime.h>
#include <hip/hip_bf16.h>

// AtomicScaleModule — CGCNN GNN forward, MFMA split-bf16 (~f32 accuracy).
// 4 groups (64 atoms) per wave; NO LDS fences (same-wave DS ops are in-order,
// compiler emits counted lgkmcnt); two-phase [32][69] wave-private slab; all
// stage outputs leave through ONE A-layout read pass (coalesced stores,
// residual add, fragment build) instead of separate C-layout store passes.
//   a = X@AE + ae_b
//   per layer: s = a@MW1[0:64]+b1 ; t = a@MW1[64:128]   (fused into producer)
//              H = sum_c relu(s + t[idx])               (gather @ head of dense)
//              agg = H@MW2 + 12*b2
//              u1 = relu(a@UW1[0:64] + agg@UW1[64:128] + ub1)
//              a' = relu(a + u1@UW2 + ub2)  (+ fused s,t of next layer)
//   af = relu(a@FX1+fb1)@FX2+fb2 ; props = af@PW^T+pb   (fused into last dense)
// S/T double-buffered across layers. nbr_fea / ne_w / ne_b dead.

constexpr int NA = 300000;

typedef short  s16x8 __attribute__((ext_vector_type(8)));
typedef float  f32x4 __attribute__((ext_vector_type(4)));

#define DEVFN static __device__ __forceinline__

DEVFN unsigned short f2bf(float x) {
  unsigned u = __float_as_uint(x);
  u += 0x7fffu + ((u >> 16) & 1u);          // RTNE
  return (unsigned short)(u >> 16);
}
DEVFN float bf2f(unsigned short h) { return __uint_as_float(((unsigned)h) << 16); }

// split x -> hi + lo bf16 pair (v_cvt_pk_bf16_f32-friendly)
DEVFN void mk_frag(const float* v, s16x8& hi, s16x8& lo) {
#pragma unroll
  for (int i = 0; i < 8; i += 2) {
    __hip_bfloat162 h2 = __float22bfloat162_rn(make_float2(v[i], v[i + 1]));
    float2 hf = __bfloat1622float2(h2);
    __hip_bfloat162 l2 = __float22bfloat162_rn(make_float2(v[i] - hf.x, v[i + 1] - hf.y));
    hi[i]     = (short)__bfloat16_as_ushort(h2.x);
    hi[i + 1] = (short)__bfloat16_as_ushort(h2.y);
    lo[i]     = (short)__bfloat16_as_ushort(l2.x);
    lo[i + 1] = (short)__bfloat16_as_ushort(l2.y);
  }
}

DEVFN f32x4 mf3(s16x8 ah, s16x8 al, s16x8 bh, s16x8 bl, f32x4 c) {
  c = __builtin_amdgcn_mfma_f32_16x16x32_bf16(al, bh, c, 0, 0, 0);
  c = __builtin_amdgcn_mfma_f32_16x16x32_bf16(ah, bl, c, 0, 0, 0);
  c = __builtin_amdgcn_mfma_f32_16x16x32_bf16(ah, bh, c, 0, 0, 0);
  return c;
}

DEVFN void ldB(const unsigned short* __restrict__ WH, const unsigned short* __restrict__ WL,
               int seg, int kt, int ct, int CT, int l, s16x8& bh, s16x8& bl) {
  size_t o = (size_t)seg + ((size_t)((kt * CT + ct) * 64 + l)) * 8;
  bh = *(const s16x8*)(WH + o);
  bl = *(const s16x8*)(WL + o);
}

DEVFN f32x4 bias4(float bv) { f32x4 c; c[0] = bv; c[1] = bv; c[2] = bv; c[3] = bv; return c; }

// one 64x64 GEMM stage for all 4 groups: 8 B-pairs, 96 MFMA.
DEVFN void stage_mm(const unsigned short* __restrict__ WH,
                    const unsigned short* __restrict__ WL,
                    int seg, int kt0,
                    const s16x8 (&fh)[4][2], const s16x8 (&fl)[4][2],
                    int l, f32x4 (&cc)[4][4]) {
#pragma unroll
  for (int ct = 0; ct < 4; ++ct)
#pragma unroll
    for (int kt = 0; kt < 2; ++kt) {
      s16x8 bh, bl; ldB(WH, WL, seg, kt0 + kt, ct, 4, l, bh, bl);
#pragma unroll
      for (int gr = 0; gr < 4; ++gr)
        cc[gr][ct] = mf3(fh[gr][kt], fl[gr][kt], bh, bl, cc[gr][ct]);
    }
}

// ---- two-phase slab transpose: half h covers features 32h..32h+31 ---------
// put: C value (row=4g+r, col=16ct+m) of group gr -> sl[16c+m][gr*17+4g+r]
// get: A-layout v[i] = feature 32h+8g+i of atom (gr,m) = sl[8g+i][gr*17+m]
DEVFN void put_half(float (*sl)[69], int m, int g, const f32x4 (&cc)[4][4], int h) {
#pragma unroll
  for (int gr = 0; gr < 4; ++gr)
#pragma unroll
    for (int c = 0; c < 2; ++c)
#pragma unroll
      for (int r = 0; r < 4; ++r)
        sl[16 * c + m][gr * 17 + 4 * g + r] = cc[gr][2 * h + c][r];
}
DEVFN void get_half(const float (*sl)[69], int m, int g, int gr, float* v) {
#pragma unroll
  for (int i = 0; i < 8; ++i) v[i] = sl[8 * g + i][gr * 17 + m];
}

DEVFN void trans_frags(float (*sl)[69], int m, int g, const f32x4 (&cc)[4][4],
                       s16x8 (&fh)[4][2], s16x8 (&fl)[4][2]) {
#pragma unroll
  for (int h = 0; h < 2; ++h) {
    put_half(sl, m, g, cc, h);
#pragma unroll
    for (int gr = 0; gr < 4; ++gr) {
      float v[8];
      get_half(sl, m, g, gr, v);
      mk_frag(v, fh[gr][h], fl[gr][h]);
    }
  }
}

DEVFN void trans_store_f32(float (*sl)[69], int m, int g, const f32x4 (&cc)[4][4],
                           float* __restrict__ B, const int (&nat)[4], const bool (&ok)[4]) {
#pragma unroll
  for (int h = 0; h < 2; ++h) {
    put_half(sl, m, g, cc, h);
#pragma unroll
    for (int gr = 0; gr < 4; ++gr) {
      float v[8];
      get_half(sl, m, g, gr, v);
      if (ok[gr]) {
        float* p = B + (size_t)nat[gr] * 64 + 32 * h + 8 * g;
        *(float4*)p = make_float4(v[0], v[1], v[2], v[3]);
        *(float4*)(p + 4) = make_float4(v[4], v[5], v[6], v[7]);
      }
    }
  }
}

DEVFN void trans_store_T(float (*sl)[69], int m, int g, const f32x4 (&cc)[4][4],
                         unsigned short* __restrict__ B, const int (&nat)[4], const bool (&ok)[4]) {
#pragma unroll
  for (int h = 0; h < 2; ++h) {
    put_half(sl, m, g, cc, h);
#pragma unroll
    for (int gr = 0; gr < 4; ++gr) {
      float v[8];
      get_half(sl, m, g, gr, v);
      if (ok[gr]) {
        uint4 q;
        unsigned* qp = (unsigned*)&q;
#pragma unroll
        for (int p = 0; p < 4; ++p)
          qp[p] = (unsigned)f2bf(v[2 * p]) | ((unsigned)f2bf(v[2 * p + 1]) << 16);
        *(uint4*)(B + (size_t)nat[gr] * 64 + 32 * h + 8 * g) = q;
      }
    }
  }
}

// ---- weight pre-conversion to B-frag layout (hi/lo bf16) ------------------
// Segments (entry offsets): AE 0 (96x64); per layer base=6144+l*24576:
//   MW1 +0 (128x64), MW2 +8192 (64x64), UW1 +12288 (128x64), UW2 +20480 (64x64)
// FX1 79872 (64x128), FX2 88064 (128x64). Total 96256 entries.
__global__ __launch_bounds__(256) void k_prep(
    const float* __restrict__ ae, const float* __restrict__ mw1,
    const float* __restrict__ mw2, const float* __restrict__ uw1,
    const float* __restrict__ uw2, const float* __restrict__ fx1,
    const float* __restrict__ fx2,
    unsigned short* __restrict__ WH, unsigned short* __restrict__ WL) {
  int e = blockIdx.x * 256 + threadIdx.x;
  const float* src;
  int K, N, loc;
  if (e < 6144) { src = ae; K = 92; N = 64; loc = e; }
  else if (e < 79872) {
    int r = e - 6144;
    int lyr = r / 24576, q = r % 24576;
    size_t l64 = (size_t)lyr * 64;
    if (q < 8192)       { src = mw1 + l64 * 128; K = 128; N = 64; loc = q; }
    else if (q < 12288) { src = mw2 + l64 * 64;  K = 64;  N = 64; loc = q - 8192; }
    else if (q < 20480) { src = uw1 + l64 * 128; K = 128; N = 64; loc = q - 12288; }
    else                { src = uw2 + l64 * 64;  K = 64;  N = 64; loc = q - 20480; }
  }
  else if (e < 88064) { src = fx1; K = 64;  N = 128; loc = e - 79872; }
  else if (e < 96256) { src = fx2; K = 128; N = 64;  loc = e - 88064; }
  else return;
  int k = (N == 64) ? (loc >> 6) : (loc >> 7);
  int j = loc & (N - 1);
  float v = (k < K) ? src[(size_t)k * N + j] : 0.f;
  unsigned short h = f2bf(v);
  int CT = N >> 4;
  int lane = ((k >> 3) & 3) * 16 + (j & 15);
  int fidx = (e - loc) + (((k >> 5) * CT + (j >> 4)) * 64 + lane) * 8 + (k & 7);
  WH[fidx] = h;
  WL[fidx] = f2bf(v - bf2f(h));
}

// ---- embed + s,t of layer 0 (64 atoms per wave) ---------------------------
__global__ __launch_bounds__(256, 2) void k_embed_st(
    const float* __restrict__ X,
    const unsigned short* __restrict__ WH, const unsigned short* __restrict__ WL,
    const float* __restrict__ aeb, const float* __restrict__ b1,
    float* __restrict__ A0, float* __restrict__ S, unsigned short* __restrict__ T) {
  __shared__ float slab[4][32][69];
  int w = threadIdx.x >> 6, l = threadIdx.x & 63, m = l & 15, g = l >> 4;
  float (*sl)[69] = slab[w];
  int nbase = blockIdx.x * 256 + w * 64;
  int nat[4]; bool ok[4];
#pragma unroll
  for (int gr = 0; gr < 4; ++gr) {
    nat[gr] = nbase + gr * 16 + m;
    ok[gr] = nat[gr] < NA;
    if (!ok[gr]) nat[gr] = NA - 1;
  }

  // a0 = X@AE + ae_b ; X fragments built per kt to bound liveness
  f32x4 ca[4][4];
#pragma unroll
  for (int gr = 0; gr < 4; ++gr)
#pragma unroll
    for (int ct = 0; ct < 4; ++ct) ca[gr][ct] = bias4(aeb[16 * ct + m]);
#pragma unroll
  for (int kt = 0; kt < 3; ++kt) {
    s16x8 xh[4], xl[4];
#pragma unroll
    for (int gr = 0; gr < 4; ++gr) {
      const float* xr = X + (size_t)nat[gr] * 92;
      float v[8];
      if (kt < 2) {
        f32x4 a = *(const f32x4*)(xr + kt * 32 + g * 8);
        f32x4 b = *(const f32x4*)(xr + kt * 32 + g * 8 + 4);
        v[0]=a[0]; v[1]=a[1]; v[2]=a[2]; v[3]=a[3]; v[4]=b[0]; v[5]=b[1]; v[6]=b[2]; v[7]=b[3];
      } else if (g < 3) {
        f32x4 a = *(const f32x4*)(xr + 64 + g * 8);
        f32x4 b = *(const f32x4*)(xr + 64 + g * 8 + 4);
        v[0]=a[0]; v[1]=a[1]; v[2]=a[2]; v[3]=a[3]; v[4]=b[0]; v[5]=b[1]; v[6]=b[2]; v[7]=b[3];
      } else {
        f32x4 a = *(const f32x4*)(xr + 88);   // 88..91 valid, 92..95 pad
        v[0]=a[0]; v[1]=a[1]; v[2]=a[2]; v[3]=a[3]; v[4]=0.f; v[5]=0.f; v[6]=0.f; v[7]=0.f;
      }
      mk_frag(v, xh[gr], xl[gr]);
    }
#pragma unroll
    for (int ct = 0; ct < 4; ++ct) {
      s16x8 bh, bl; ldB(WH, WL, 0, kt, ct, 4, l, bh, bl);
#pragma unroll
      for (int gr = 0; gr < 4; ++gr)
        ca[gr][ct] = mf3(xh[gr], xl[gr], bh, bl, ca[gr][ct]);
    }
  }

  // transpose a0: store A0 coalesced + build fragments, one read pass
  s16x8 ah[4][2], al[4][2];
#pragma unroll
  for (int h = 0; h < 2; ++h) {
    put_half(sl, m, g, ca, h);
#pragma unroll
    for (int gr = 0; gr < 4; ++gr) {
      float v[8];
      get_half(sl, m, g, gr, v);
      if (ok[gr]) {
        float* p = A0 + (size_t)nat[gr] * 64 + 32 * h + 8 * g;
        *(float4*)p = make_float4(v[0], v[1], v[2], v[3]);
        *(float4*)(p + 4) = make_float4(v[4], v[5], v[6], v[7]);
      }
      mk_frag(v, ah[gr][h], al[gr][h]);
    }
  }

  // s = a0@MW1[0:64] + b1
  f32x4 cs[4][4];
#pragma unroll
  for (int gr = 0; gr < 4; ++gr)
#pragma unroll
    for (int ct = 0; ct < 4; ++ct) cs[gr][ct] = bias4(b1[16 * ct + m]);
  stage_mm(WH, WL, 6144, 0, ah, al, l, cs);
  trans_store_f32(sl, m, g, cs, S, nat, ok);

  // t = a0@MW1[64:128]
  f32x4 cT[4][4];
#pragma unroll
  for (int gr = 0; gr < 4; ++gr)
#pragma unroll
    for (int ct = 0; ct < 4; ++ct) cT[gr][ct] = bias4(0.f);
  stage_mm(WH, WL, 6144, 2, ah, al, l, cT);
  trans_store_T(sl, m, g, cT, T, nat, ok);
}

// ---- fused: gather + dense chain (+ next-layer s,t | + fx tail) -----------
template <int HAS_NEXT, int HAS_FX>
__global__ __launch_bounds__(256, 2) void k_dense(
    const float* __restrict__ A, const float* __restrict__ S,
    const unsigned short* __restrict__ T, const int* __restrict__ IDX,
    const unsigned short* __restrict__ WH, const unsigned short* __restrict__ WL,
    int segW2, int segU1, int segU2, int segWn,
    const float* __restrict__ b2, const float* __restrict__ ub1,
    const float* __restrict__ ub2, const float* __restrict__ bn,
    const float* __restrict__ fb1, const float* __restrict__ fb2,
    const float* __restrict__ PW, const float* __restrict__ PB,
    float* __restrict__ Anew, float* __restrict__ Sout,
    unsigned short* __restrict__ Tout,
    float* __restrict__ AF, float* __restrict__ PR) {
  __shared__ float slab[4][32][69];
  int w = threadIdx.x >> 6, l = threadIdx.x & 63, m = l & 15, g = l >> 4;
  float (*sl)[69] = slab[w];
  int nbase = blockIdx.x * 256 + w * 64;
  int nat[4]; bool ok[4];
#pragma unroll
  for (int gr = 0; gr < 4; ++gr) {
    nat[gr] = nbase + gr * 16 + m;
    ok[gr] = nat[gr] < NA;
    if (!ok[gr]) nat[gr] = NA - 1;
  }

  // gather: H = sum_c relu(s + t[idx]); fragments built directly.
  s16x8 hh[4][2], hl[4][2];
#pragma unroll
  for (int gr = 0; gr < 4; ++gr) {
    const int* ip = IDX + (size_t)nat[gr] * 12;
    int4 i0 = *(const int4*)ip;
    int4 i1 = *(const int4*)(ip + 4);
    int4 i2 = *(const int4*)(ip + 8);
    int idxs[12] = {i0.x, i0.y, i0.z, i0.w, i1.x, i1.y, i1.z, i1.w,
                    i2.x, i2.y, i2.z, i2.w};
#pragma unroll
    for (int kt = 0; kt < 2; ++kt) {
      int f0 = 32 * kt + 8 * g;
      const float* sp = S + (size_t)nat[gr] * 64 + f0;
      f32x4 s0 = *(const f32x4*)sp;
      f32x4 s1 = *(const f32x4*)(sp + 4);
      float h[8] = {0, 0, 0, 0, 0, 0, 0, 0};
#pragma unroll
      for (int c = 0; c < 12; ++c) {
        uint4 tv = *(const uint4*)(T + (size_t)idxs[c] * 64 + f0);
        h[0] += fmaxf(s0[0] + bf2f((unsigned short)(tv.x & 0xffff)), 0.f);
        h[1] += fmaxf(s0[1] + bf2f((unsigned short)(tv.x >> 16)), 0.f);
        h[2] += fmaxf(s0[2] + bf2f((unsigned short)(tv.y & 0xffff)), 0.f);
        h[3] += fmaxf(s0[3] + bf2f((unsigned short)(tv.y >> 16)), 0.f);
        h[4] += fmaxf(s1[0] + bf2f((unsigned short)(tv.z & 0xffff)), 0.f);
        h[5] += fmaxf(s1[1] + bf2f((unsigned short)(tv.z >> 16)), 0.f);
        h[6] += fmaxf(s1[2] + bf2f((unsigned short)(tv.w & 0xffff)), 0.f);
        h[7] += fmaxf(s1[3] + bf2f((unsigned short)(tv.w >> 16)), 0.f);
      }
      mk_frag(h, hh[gr][kt], hl[gr][kt]);
    }
  }

  // agg = H@W2 + 12*b2
  f32x4 cg[4][4];
#pragma unroll
  for (int gr = 0; gr < 4; ++gr)
#pragma unroll
    for (int ct = 0; ct < 4; ++ct) cg[gr][ct] = bias4(12.f * b2[16 * ct + m]);
  stage_mm(WH, WL, segW2, 0, hh, hl, l, cg);

  // u1: a-part first (a frags die before q frags are built -> lower peak regs)
  f32x4 cu[4][4];
#pragma unroll
  for (int gr = 0; gr < 4; ++gr)
#pragma unroll
    for (int ct = 0; ct < 4; ++ct) cu[gr][ct] = bias4(ub1[16 * ct + m]);
  {
    s16x8 arh[4][2], arl[4][2];
#pragma unroll
    for (int gr = 0; gr < 4; ++gr)
#pragma unroll
      for (int kt = 0; kt < 2; ++kt) {
        const float* p8 = A + (size_t)nat[gr] * 64 + kt * 32 + g * 8;
        f32x4 a = *(const f32x4*)p8;
        f32x4 b = *(const f32x4*)(p8 + 4);
        float v[8] = {a[0], a[1], a[2], a[3], b[0], b[1], b[2], b[3]};
        mk_frag(v, arh[gr][kt], arl[gr][kt]);
      }
    stage_mm(WH, WL, segU1, 0, arh, arl, l, cu);
  }
  {
    s16x8 qh[4][2], ql[4][2];
    trans_frags(sl, m, g, cg, qh, ql);
    stage_mm(WH, WL, segU1, 2, qh, ql, l, cu);
  }
#pragma unroll
  for (int gr = 0; gr < 4; ++gr)
#pragma unroll
    for (int ct = 0; ct < 4; ++ct)
#pragma unroll
      for (int r = 0; r < 4; ++r) cu[gr][ct][r] = fmaxf(cu[gr][ct][r], 0.f);

  // upd = u1@U2 + ub2
  f32x4 cd[4][4];
#pragma unroll
  for (int gr = 0; gr < 4; ++gr)
#pragma unroll
    for (int ct = 0; ct < 4; ++ct) cd[gr][ct] = bias4(ub2[16 * ct + m]);
  {
    s16x8 uh[4][2], ul[4][2];
    trans_frags(sl, m, g, cu, uh, ul);
    stage_mm(WH, WL, segU2, 0, uh, ul, l, cd);
  }

  // a' = relu(a + upd): transpose upd, coalesced residual re-read, coalesced
  // store, fragments for the next stages — all in one A-layout pass.
  s16x8 anh[4][2], anl[4][2];
#pragma unroll
  for (int h = 0; h < 2; ++h) {
    put_half(sl, m, g, cd, h);
#pragma unroll
    for (int gr = 0; gr < 4; ++gr) {
      float v[8];
      get_half(sl, m, g, gr, v);
      const float* ap = A + (size_t)nat[gr] * 64 + 32 * h + 8 * g;
      f32x4 a0 = *(const f32x4*)ap;
      f32x4 a1 = *(const f32x4*)(ap + 4);
#pragma unroll
      for (int i = 0; i < 4; ++i) {
        v[i]     = fmaxf(v[i] + a0[i], 0.f);
        v[i + 4] = fmaxf(v[i + 4] + a1[i], 0.f);
      }
      if (ok[gr]) {
        float* p = Anew + (size_t)nat[gr] * 64 + 32 * h + 8 * g;
        *(float4*)p = make_float4(v[0], v[1], v[2], v[3]);
        *(float4*)(p + 4) = make_float4(v[4], v[5], v[6], v[7]);
      }
      if constexpr (HAS_NEXT || HAS_FX) mk_frag(v, anh[gr][h], anl[gr][h]);
    }
  }

  if constexpr (HAS_NEXT) {
    // s_next
    f32x4 cs[4][4];
#pragma unroll
    for (int gr = 0; gr < 4; ++gr)
#pragma unroll
      for (int ct = 0; ct < 4; ++ct) cs[gr][ct] = bias4(bn[16 * ct + m]);
    stage_mm(WH, WL, segWn, 0, anh, anl, l, cs);
    trans_store_f32(sl, m, g, cs, Sout, nat, ok);

    // t_next
    f32x4 cT[4][4];
#pragma unroll
    for (int gr = 0; gr < 4; ++gr)
#pragma unroll
      for (int ct = 0; ct < 4; ++ct) cT[gr][ct] = bias4(0.f);
    stage_mm(WH, WL, segWn, 2, anh, anl, l, cT);
    trans_store_T(sl, m, g, cT, Tout, nat, ok);
  }

  if constexpr (HAS_FX) {
    // af = relu(raw@FX1+fb1)@FX2+fb2, hidden 128 in two 64-col rounds
    f32x4 cf[4][4];
#pragma unroll
    for (int gr = 0; gr < 4; ++gr)
#pragma unroll
      for (int ct = 0; ct < 4; ++ct) cf[gr][ct] = bias4(fb2[16 * ct + m]);

#pragma unroll
    for (int hr = 0; hr < 2; ++hr) {
      f32x4 chh[4][4];
#pragma unroll
      for (int gr = 0; gr < 4; ++gr)
#pragma unroll
        for (int ct = 0; ct < 4; ++ct)
          chh[gr][ct] = bias4(fb1[16 * (4 * hr + ct) + m]);
#pragma unroll
      for (int ct = 0; ct < 4; ++ct)
#pragma unroll
        for (int kt = 0; kt < 2; ++kt) {
          s16x8 bh, bl; ldB(WH, WL, 79872, kt, 4 * hr + ct, 8, l, bh, bl);
#pragma unroll
          for (int gr = 0; gr < 4; ++gr)
            chh[gr][ct] = mf3(anh[gr][kt], anl[gr][kt], bh, bl, chh[gr][ct]);
        }
#pragma unroll
      for (int gr = 0; gr < 4; ++gr)
#pragma unroll
        for (int ct = 0; ct < 4; ++ct)
#pragma unroll
          for (int r = 0; r < 4; ++r) chh[gr][ct][r] = fmaxf(chh[gr][ct][r], 0.f);

      s16x8 hfh[4][2], hfl[4][2];
      trans_frags(sl, m, g, chh, hfh, hfl);
      stage_mm(WH, WL, 88064, 2 * hr, hfh, hfl, l, cf);
    }

    // AF store + props partials in the same A-layout pass
    float pp[4][4];
#pragma unroll
    for (int gr = 0; gr < 4; ++gr)
#pragma unroll
      for (int p = 0; p < 4; ++p) pp[gr][p] = 0.f;
#pragma unroll
    for (int h = 0; h < 2; ++h) {
      put_half(sl, m, g, cf, h);
      f32x4 pw0[4], pw1[4];
#pragma unroll
      for (int p = 0; p < 4; ++p) {
        const float* q = PW + p * 64 + 32 * h + 8 * g;
        pw0[p] = *(const f32x4*)q;
        pw1[p] = *(const f32x4*)(q + 4);
      }
#pragma unroll
      for (int gr = 0; gr < 4; ++gr) {
        float v[8];
        get_half(sl, m, g, gr, v);
        if (ok[gr]) {
          float* p = AF + (size_t)nat[gr] * 64 + 32 * h + 8 * g;
          *(float4*)p = make_float4(v[0], v[1], v[2], v[3]);
          *(float4*)(p + 4) = make_float4(v[4], v[5], v[6], v[7]);
        }
#pragma unroll
        for (int p = 0; p < 4; ++p)
#pragma unroll
          for (int i = 0; i < 4; ++i)
            pp[gr][p] += v[i] * pw0[p][i] + v[i + 4] * pw1[p][i];
      }
    }
    // reduce over g lanes (l^16, l^32), then lane (m,g) writes prop p=g
#pragma unroll
    for (int gr = 0; gr < 4; ++gr) {
      float r0 = pp[gr][0], r1 = pp[gr][1], r2 = pp[gr][2], r3 = pp[gr][3];
      r0 += __shfl_xor(r0, 16); r0 += __shfl_xor(r0, 32);
      r1 += __shfl_xor(r1, 16); r1 += __shfl_xor(r1, 32);
      r2 += __shfl_xor(r2, 16); r2 += __shfl_xor(r2, 32);
      r3 += __shfl_xor(r3, 16); r3 += __shfl_xor(r3, 32);
      float sel = (g == 0) ? r0 : (g == 1) ? r1 : (g == 2) ? r2 : r3;
      if (ok[gr]) PR[(size_t)nat[gr] * 4 + g] = sel + PB[g];
    }
  }
}

extern "C" void kernel_launch(void* const* d_in, const int* in_sizes, int n_in,
                              void* d_out, int out_size, void* d_ws, size_t ws_size,
                              hipStream_t stream) {
  const float* atom_fea = (const float*)d_in[0];
  const int*   nbr_idx  = (const int*)d_in[2];
  const float* ae_w   = (const float*)d_in[3];
  const float* ae_b   = (const float*)d_in[4];
  const float* msg_w1 = (const float*)d_in[7];
  const float* msg_b1 = (const float*)d_in[8];
  const float* msg_w2 = (const float*)d_in[9];
  const float* msg_b2 = (const float*)d_in[10];
  const float* upd_w1 = (const float*)d_in[11];
  const float* upd_b1 = (const float*)d_in[12];
  const float* upd_w2 = (const float*)d_in[13];
  const float* upd_b2 = (const float*)d_in[14];
  const float* fx_w1  = (const float*)d_in[15];
  const float* fx_b1  = (const float*)d_in[16];
  const float* fx_w2  = (const float*)d_in[17];
  const float* fx_b2  = (const float*)d_in[18];
  const float* prop_w = (const float*)d_in[19];
  const float* prop_b = (const float*)d_in[20];

  float* props   = (float*)d_out;
  float* af_reg  = props + (size_t)NA * 4;
  float* raw_reg = af_reg + (size_t)NA * 64;
  float* S0 = (float*)d_ws;
  float* S1 = S0 + (size_t)NA * 64;
  unsigned short* T0 = (unsigned short*)(S1 + (size_t)NA * 64);
  unsigned short* T1 = T0 + (size_t)NA * 64;
  unsigned short* WHp = T1 + (size_t)NA * 64;
  unsigned short* WLp = WHp + 96256;

  k_prep<<<376, 256, 0, stream>>>(ae_w, msg_w1, msg_w2, upd_w1, upd_w2,
                                  fx_w1, fx_w2, WHp, WLp);

  int ngrid = (NA + 255) / 256;   // 1172
  k_embed_st<<<ngrid, 256, 0, stream>>>(atom_fea, WHp, WLp, ae_b, msg_b1,
                                        af_reg, S0, T0);

  const int base0 = 6144, base1 = 6144 + 24576, base2 = 6144 + 2 * 24576;

  // layer 0: A0(af_reg) -> A1(raw_reg); S0/T0 -> S1/T1
  k_dense<1, 0><<<ngrid, 256, 0, stream>>>(
      af_reg, S0, T0, nbr_idx, WHp, WLp,
      base0 + 8192, base0 + 12288, base0 + 20480, base1,
      msg_b2, upd_b1, upd_b2, msg_b1 + 64,
      fx_b1, fx_b2, prop_w, prop_b,
      raw_reg, S1, T1, nullptr, nullptr);

  // layer 1: A1(raw_reg) -> A2(af_reg); S1/T1 -> S0/T0
  k_dense<1, 0><<<ngrid, 256, 0, stream>>>(
      raw_reg, S1, T1, nbr_idx, WHp, WLp,
      base1 + 8192, base1 + 12288, base1 + 20480, base2,
      msg_b2 + 64, upd_b1 + 64, upd_b2 + 64, msg_b1 + 128,
      fx_b1, fx_b2, prop_w, prop_b,
      af_reg, S0, T0, nullptr, nullptr);

  // layer 2 + fx: A2(af_reg) -> raw(raw_reg); af->af_reg, props->d_out
  k_dense<0, 1><<<ngrid, 256, 0, stream>>>(
      af_reg, S0, T0, nbr_idx, WHp, WLp,
      base2 + 8192, base2 + 12288, base2 + 20480, 0,
      msg_b2 + 128, upd_b1 + 128, upd_b2 + 128, msg_b1,
      fx_b1, fx_b2, prop_w, prop_b,
      raw_reg, S1, T1, af_reg, props);
}